// Round 8
// baseline (132.827 us; speedup 1.0000x reference)
//
#include <hip/hip_runtime.h>

#define S_ 512
#define D_ 768
#define NH 12
#define HD 64
#define RK 16
#define D3 2304
#define LN_EPS 1e-5f

// odd Taylor tanh coefficients (deg-5; |d|<~0.35)
#define C3B (-0.3333333433f)
#define C5B (0.1333333403f)

typedef __attribute__((ext_vector_type(8))) short bfrag;
typedef __attribute__((ext_vector_type(4))) float ffrag;

__device__ __forceinline__ unsigned short f2bf(float f) {
    unsigned int u = __float_as_uint(f);
    unsigned int r = (u + 0x7FFFu + ((u >> 16) & 1u)) >> 16;   // RNE
    return (unsigned short)r;
}

// Pade [3/4] tanh for g_val (|x|<=0.02)
__device__ __forceinline__ float fast_tanh(float x) {
    float x2 = x * x;
    float num = x * __fmaf_rn(x2, 10.f, 105.f);
    float den = __fmaf_rn(x2 + 45.f, x2, 105.f);
    return num * __builtin_amdgcn_rcpf(den);
}

// ---------------- Kernel 1: LayerNorm + h = silu(xn @ W1^T), one wave/row;
// also packs Wv -> bf16 (independent side job) -------------------------------
__global__ __launch_bounds__(256) void k_ln(
    const float* __restrict__ x, const float* __restrict__ gamma,
    const float* __restrict__ beta, const float* __restrict__ W1,
    const float* __restrict__ Wv, unsigned short* __restrict__ Wvb,
    float* __restrict__ hout)
{
    const int row = blockIdx.x * 4 + (threadIdx.x >> 6);
    const int lane = threadIdx.x & 63;
    const float4* xr = (const float4*)(x + (size_t)row * D_);
    float4 a = xr[lane], b = xr[lane + 64], c = xr[lane + 128];
    float s = a.x + a.y + a.z + a.w + b.x + b.y + b.z + b.w + c.x + c.y + c.z + c.w;
    float sq = a.x*a.x + a.y*a.y + a.z*a.z + a.w*a.w
             + b.x*b.x + b.y*b.y + b.z*b.z + b.w*b.w
             + c.x*c.x + c.y*c.y + c.z*c.z + c.w*c.w;
    #pragma unroll
    for (int m = 1; m < 64; m <<= 1) { s += __shfl_xor(s, m); sq += __shfl_xor(sq, m); }
    float mean = s * (1.f / D_);
    float rstd = rsqrtf(sq * (1.f / D_) - mean * mean + LN_EPS);
    const float4* g4 = (const float4*)gamma;
    const float4* b4 = (const float4*)beta;
    float4 ga_ = g4[lane], gb_ = g4[lane + 64], gc_ = g4[lane + 128];
    float4 ba_ = b4[lane], bb_ = b4[lane + 64], bc_ = b4[lane + 128];
    float4 na, nb, nc;
    na.x = (a.x-mean)*rstd*ga_.x + ba_.x; na.y = (a.y-mean)*rstd*ga_.y + ba_.y;
    na.z = (a.z-mean)*rstd*ga_.z + ba_.z; na.w = (a.w-mean)*rstd*ga_.w + ba_.w;
    nb.x = (b.x-mean)*rstd*gb_.x + bb_.x; nb.y = (b.y-mean)*rstd*gb_.y + bb_.y;
    nb.z = (b.z-mean)*rstd*gb_.z + bb_.z; nb.w = (b.w-mean)*rstd*gb_.w + bb_.w;
    nc.x = (c.x-mean)*rstd*gc_.x + bc_.x; nc.y = (c.y-mean)*rstd*gc_.y + bc_.y;
    nc.z = (c.z-mean)*rstd*gc_.z + bc_.z; nc.w = (c.w-mean)*rstd*gc_.w + bc_.w;

    float hval = 0.f;
    #pragma unroll
    for (int r = 0; r < RK; ++r) {
        const float4* wr = (const float4*)(W1 + (size_t)r * D_);
        float4 wa = wr[lane], wb = wr[lane + 64], wc = wr[lane + 128];
        float p = na.x*wa.x + na.y*wa.y + na.z*wa.z + na.w*wa.w
                + nb.x*wb.x + nb.y*wb.y + nb.z*wb.z + nb.w*wb.w
                + nc.x*wc.x + nc.y*wc.y + nc.z*wc.z + nc.w*wc.w;
        #pragma unroll
        for (int m = 1; m < 64; m <<= 1) p += __shfl_xor(p, m);
        if (lane == r) hval = p;
    }
    if (lane < RK)
        hout[row * RK + lane] = hval * __builtin_amdgcn_rcpf(1.f + __expf(-hval));

    // Wv -> bf16 pack: 589824 elems / 32768 threads = 18 each
    const int gid = blockIdx.x * 256 + threadIdx.x;
    #pragma unroll
    for (int l = 0; l < 18; ++l)
        Wvb[gid + 32768 * l] = f2bf(Wv[gid + 32768 * l]);
}

// ---------------- Kernel 2: A-slice GEMM (K=16) fused with:
//  v-blocks : write bf16 Avb
//  q-blocks : L = [q | aqp'' | x | x^2 | x^3 | x^4], I[row] = -C5 sum w x^5
//  k-blocks : R = [akp'' | k | P1..P4],             J[row] = sum w(b+C3b^3+C5b^5)
__global__ __launch_bounds__(256) void k_amix(
    const float* __restrict__ h, const float* __restrict__ W2,
    const float* __restrict__ Wq, const float* __restrict__ Wk,
    const float* __restrict__ g_attn,
    const float* __restrict__ qb, const float* __restrict__ kb,
    const float* __restrict__ relb, const float* __restrict__ g_rel,
    unsigned short* __restrict__ Avb,
    unsigned short* __restrict__ L, unsigned short* __restrict__ R,
    float* __restrict__ J, float* __restrict__ I)
{
    __shared__ float hs[64 * 17];
    __shared__ float w2s[64 * 17];
    __shared__ float At[64 * 68];    // [s][dd]
    __shared__ float Ws[64 * 68];    // [dd][i] transposed
    const int b = blockIdx.x;
    const int t = threadIdx.x;
    const int tx = t & 15, ty = t >> 4;

    int s0, c0, which = 0, hh = 0;
    bool qk = (b < 192);
    if (qk) { which = b & 1; hh = (b >> 1) % NH; s0 = ((b >> 1) / NH) * 64; c0 = which * D_ + hh * HD; }
    else    { int b2 = b - 192; s0 = (b2 / NH) * 64; hh = b2 % NH; c0 = 1536 + hh * HD; }

    {
        int r = t >> 2, q = (t & 3) * 4;
        float4 hv = *(const float4*)(h + (size_t)(s0 + r) * RK + q);
        hs[r*17+q] = hv.x; hs[r*17+q+1] = hv.y; hs[r*17+q+2] = hv.z; hs[r*17+q+3] = hv.w;
        float4 wv = *(const float4*)(W2 + (size_t)(c0 + r) * RK + q);
        w2s[r*17+q] = wv.x; w2s[r*17+q+1] = wv.y; w2s[r*17+q+2] = wv.z; w2s[r*17+q+3] = wv.w;
    }
    if (qk) {
        const float* Wsrc = which ? Wk : Wq;
        #pragma unroll
        for (int l = 0; l < 4; ++l) {
            int m = t + 256 * l;
            int i = m >> 4, dq = (m & 15) * 4;
            float4 wv = *(const float4*)(Wsrc + (size_t)i * HD + dq);
            Ws[(dq+0)*68+i] = wv.x; Ws[(dq+1)*68+i] = wv.y;
            Ws[(dq+2)*68+i] = wv.z; Ws[(dq+3)*68+i] = wv.w;
        }
    }
    __syncthreads();

    float acc[4][4] = {};
    #pragma unroll
    for (int k = 0; k < RK; ++k) {
        float a0 = hs[(4*ty+0)*17+k], a1 = hs[(4*ty+1)*17+k];
        float a2 = hs[(4*ty+2)*17+k], a3 = hs[(4*ty+3)*17+k];
        float w0 = w2s[(4*tx+0)*17+k], w1 = w2s[(4*tx+1)*17+k];
        float w2v = w2s[(4*tx+2)*17+k], w3 = w2s[(4*tx+3)*17+k];
        acc[0][0]=__fmaf_rn(a0,w0,acc[0][0]); acc[0][1]=__fmaf_rn(a0,w1,acc[0][1]);
        acc[0][2]=__fmaf_rn(a0,w2v,acc[0][2]); acc[0][3]=__fmaf_rn(a0,w3,acc[0][3]);
        acc[1][0]=__fmaf_rn(a1,w0,acc[1][0]); acc[1][1]=__fmaf_rn(a1,w1,acc[1][1]);
        acc[1][2]=__fmaf_rn(a1,w2v,acc[1][2]); acc[1][3]=__fmaf_rn(a1,w3,acc[1][3]);
        acc[2][0]=__fmaf_rn(a2,w0,acc[2][0]); acc[2][1]=__fmaf_rn(a2,w1,acc[2][1]);
        acc[2][2]=__fmaf_rn(a2,w2v,acc[2][2]); acc[2][3]=__fmaf_rn(a2,w3,acc[2][3]);
        acc[3][0]=__fmaf_rn(a3,w0,acc[3][0]); acc[3][1]=__fmaf_rn(a3,w1,acc[3][1]);
        acc[3][2]=__fmaf_rn(a3,w2v,acc[3][2]); acc[3][3]=__fmaf_rn(a3,w3,acc[3][3]);
    }

    if (!qk) {   // value field -> bf16 Avb
        #pragma unroll
        for (int i = 0; i < 4; ++i) {
            ushort4 v = make_ushort4(f2bf(acc[i][0]), f2bf(acc[i][1]),
                                     f2bf(acc[i][2]), f2bf(acc[i][3]));
            *(ushort4*)(Avb + (size_t)(s0 + 4*ty + i) * D_ + hh * HD + 4*tx) = v;
        }
        return;
    }

    // stash A values for the projection phase
    #pragma unroll
    for (int i = 0; i < 4; ++i)
        *(float4*)(At + (4*ty + i) * 68 + 4*tx) =
            make_float4(acc[i][0], acc[i][1], acc[i][2], acc[i][3]);

    // raw base copy (q->L[0:64) or k->R[64:128)) — no LDS dependency
    {
        unsigned short* P = which ? R : L;
        const float* src = which ? kb : qb;
        const int segb = which ? 64 : 0;
        int r = t >> 2, cq = (t & 3) * 16;
        const float* sp = src + ((size_t)(hh * S_ + s0 + r)) * HD + cq;
        unsigned short* dp = P + ((size_t)(hh * S_ + s0 + r)) * 384 + segb + cq;
        #pragma unroll
        for (int u = 0; u < 4; ++u) {
            float4 v = *(const float4*)(sp + 4*u);
            *(ushort4*)(dp + 4*u) = make_ushort4(f2bf(v.x), f2bf(v.y), f2bf(v.z), f2bf(v.w));
        }
    }

    // per-dd weights w = relb * g_rel for this head
    float w_[4];
    {
        float grv = g_rel[hh];
        float4 rb4 = *(const float4*)(relb + hh * HD + 4*tx);
        w_[0] = rb4.x * grv; w_[1] = rb4.y * grv; w_[2] = rb4.z * grv; w_[3] = rb4.w * grv;
    }

    // power/poly segments + row-reduction partials
    float red[4];
    #pragma unroll
    for (int i = 0; i < 4; ++i) {
        size_t rb = ((size_t)(hh * S_ + s0 + 4*ty + i)) * 384;
        float partial = 0.f;
        ushort4 o1, o2, o3, o4;
        if (which == 0) {
            #pragma unroll
            for (int j = 0; j < 4; ++j) {
                float xv = acc[i][j];
                float x2 = xv*xv, x3 = x2*xv, x4 = x2*x2, x5 = x3*x2;
                ((unsigned short*)&o1)[j] = f2bf(xv);
                ((unsigned short*)&o2)[j] = f2bf(x2);
                ((unsigned short*)&o3)[j] = f2bf(x3);
                ((unsigned short*)&o4)[j] = f2bf(x4);
                partial += w_[j] * x5;
            }
            *(ushort4*)(L + rb + 128 + 4*tx) = o1;
            *(ushort4*)(L + rb + 192 + 4*tx) = o2;
            *(ushort4*)(L + rb + 256 + 4*tx) = o3;
            *(ushort4*)(L + rb + 320 + 4*tx) = o4;
        } else {
            #pragma unroll
            for (int j = 0; j < 4; ++j) {
                float bv = acc[i][j];
                float b2 = bv*bv, b3 = b2*bv, b4 = b2*b2, b5 = b3*b2;
                float w = w_[j];
                ((unsigned short*)&o1)[j] = f2bf(w * (-1.f - 3.f*C3B*b2 - 5.f*C5B*b4));
                ((unsigned short*)&o2)[j] = f2bf(w * (3.f*C3B*bv + 10.f*C5B*b3));
                ((unsigned short*)&o3)[j] = f2bf(w * (-C3B - 10.f*C5B*b2));
                ((unsigned short*)&o4)[j] = f2bf(w * (5.f*C5B*bv));
                partial += w * (bv + C3B*b3 + C5B*b5);
            }
            *(ushort4*)(R + rb + 128 + 4*tx) = o1;
            *(ushort4*)(R + rb + 192 + 4*tx) = o2;
            *(ushort4*)(R + rb + 256 + 4*tx) = o3;
            *(ushort4*)(R + rb + 320 + 4*tx) = o4;
        }
        red[i] = partial;
    }
    #pragma unroll
    for (int mm = 1; mm < 16; mm <<= 1) {
        #pragma unroll
        for (int i = 0; i < 4; ++i) red[i] += __shfl_xor(red[i], mm);
    }
    if (tx == 0) {
        #pragma unroll
        for (int i = 0; i < 4; ++i) {
            int row = hh * S_ + s0 + 4*ty + i;
            if (which == 0) I[row] = -C5B * red[i];
            else            J[row] = red[i];
        }
    }
    __syncthreads();

    // projection: pacc[s][i] = sum_dd At[s][dd] * W[i][dd]  (then * 0.125*g_attn)
    float pacc[4][4] = {};
    #pragma unroll 8
    for (int dd = 0; dd < HD; ++dd) {
        float a0 = At[(4*ty+0)*68+dd], a1 = At[(4*ty+1)*68+dd];
        float a2 = At[(4*ty+2)*68+dd], a3 = At[(4*ty+3)*68+dd];
        float4 wv = *(const float4*)(Ws + dd*68 + 4*tx);
        pacc[0][0]=__fmaf_rn(a0,wv.x,pacc[0][0]); pacc[0][1]=__fmaf_rn(a0,wv.y,pacc[0][1]);
        pacc[0][2]=__fmaf_rn(a0,wv.z,pacc[0][2]); pacc[0][3]=__fmaf_rn(a0,wv.w,pacc[0][3]);
        pacc[1][0]=__fmaf_rn(a1,wv.x,pacc[1][0]); pacc[1][1]=__fmaf_rn(a1,wv.y,pacc[1][1]);
        pacc[1][2]=__fmaf_rn(a1,wv.z,pacc[1][2]); pacc[1][3]=__fmaf_rn(a1,wv.w,pacc[1][3]);
        pacc[2][0]=__fmaf_rn(a2,wv.x,pacc[2][0]); pacc[2][1]=__fmaf_rn(a2,wv.y,pacc[2][1]);
        pacc[2][2]=__fmaf_rn(a2,wv.z,pacc[2][2]); pacc[2][3]=__fmaf_rn(a2,wv.w,pacc[2][3]);
        pacc[3][0]=__fmaf_rn(a3,wv.x,pacc[3][0]); pacc[3][1]=__fmaf_rn(a3,wv.y,pacc[3][1]);
        pacc[3][2]=__fmaf_rn(a3,wv.z,pacc[3][2]); pacc[3][3]=__fmaf_rn(a3,wv.w,pacc[3][3]);
    }
    float sc = 0.125f * g_attn[hh];
    #pragma unroll
    for (int i = 0; i < 4; ++i) {
        size_t rb = ((size_t)(hh * S_ + s0 + 4*ty + i)) * 384;
        ushort4 o = make_ushort4(f2bf(pacc[i][0]*sc), f2bf(pacc[i][1]*sc),
                                 f2bf(pacc[i][2]*sc), f2bf(pacc[i][3]*sc));
        unsigned short* dst = which ? (R + rb + 4*tx) : (L + rb + 64 + 4*tx);
        *(ushort4*)dst = o;
    }
}

// ---------------- Kernel 3: merged MFMA kernel.
//  z < 12, x < 8 : gauge[h=z] 64x64 tile = L @ R^T (K=384) + J[col] + I[row]
//  z == 12       : dv 64x64 tile = tanh(g_val[e]) * (Avb @ Wvb^T) (K=768)
//  Operands straight from global; no LDS, no barriers. -----------------------
__global__ __launch_bounds__(256) void k_mm(
    const unsigned short* __restrict__ L, const unsigned short* __restrict__ R,
    const float* __restrict__ J, const float* __restrict__ I,
    const unsigned short* __restrict__ Avb, const unsigned short* __restrict__ Wvb,
    const float* __restrict__ g_val,
    float* __restrict__ out, float* __restrict__ dv)
{
    const int z = blockIdx.z;
    const int t = threadIdx.x;
    const int wave = t >> 6, lane = t & 63;
    const int wy = wave >> 1, wx = wave & 1;
    const int m = lane & 15, q = lane >> 4;

    ffrag acc00 = {0.f,0.f,0.f,0.f}, acc01 = acc00, acc10 = acc00, acc11 = acc00;

    if (z < NH) {
        if (blockIdx.x >= 8) return;
        const int h = z;
        const int ib = blockIdx.y * 64 + wy * 32, jb = blockIdx.x * 64 + wx * 32;

        const unsigned short* pa0 = L + ((size_t)(h * S_) + ib + m) * 384 + 8 * q;
        const unsigned short* pa1 = pa0 + 16 * 384;
        const unsigned short* pb0 = R + ((size_t)(h * S_) + jb + m) * 384 + 8 * q;
        const unsigned short* pb1 = pb0 + 16 * 384;

        #pragma unroll
        for (int kc = 0; kc < 12; ++kc) {
            bfrag a0 = *(const bfrag*)(pa0 + kc * 32);
            bfrag a1 = *(const bfrag*)(pa1 + kc * 32);
            bfrag b0 = *(const bfrag*)(pb0 + kc * 32);
            bfrag b1 = *(const bfrag*)(pb1 + kc * 32);
            acc00 = __builtin_amdgcn_mfma_f32_16x16x32_bf16(a0, b0, acc00, 0, 0, 0);
            acc01 = __builtin_amdgcn_mfma_f32_16x16x32_bf16(a0, b1, acc01, 0, 0, 0);
            acc10 = __builtin_amdgcn_mfma_f32_16x16x32_bf16(a1, b0, acc10, 0, 0, 0);
            acc11 = __builtin_amdgcn_mfma_f32_16x16x32_bf16(a1, b1, acc11, 0, 0, 0);
        }

        const float Jc0 = J[h * S_ + jb + m];
        const float Jc1 = J[h * S_ + jb + 16 + m];
        float* ob = out + ((size_t)h * S_) * S_;
        #pragma unroll
        for (int reg = 0; reg < 4; ++reg) {
            int r0 = ib + 4 * q + reg, r1 = r0 + 16;
            float i0v = I[h * S_ + r0];
            ob[(size_t)r0 * S_ + jb + m]      = acc00[reg] + Jc0 + i0v;
            ob[(size_t)r0 * S_ + jb + 16 + m] = acc01[reg] + Jc1 + i0v;
            float i1v = I[h * S_ + r1];
            ob[(size_t)r1 * S_ + jb + m]      = acc10[reg] + Jc0 + i1v;
            ob[(size_t)r1 * S_ + jb + 16 + m] = acc11[reg] + Jc1 + i1v;
        }
    } else {
        // delta_v tile: rows = s, cols = e, K = 768
        const int sb = blockIdx.y * 64 + wy * 32, eb = blockIdx.x * 64 + wx * 32;

        const unsigned short* pa0 = Avb + (size_t)(sb + m) * D_ + 8 * q;
        const unsigned short* pa1 = pa0 + 16 * D_;
        const unsigned short* pb0 = Wvb + (size_t)(eb + m) * D_ + 8 * q;
        const unsigned short* pb1 = pb0 + 16 * D_;

        #pragma unroll 6
        for (int kc = 0; kc < 24; ++kc) {
            bfrag a0 = *(const bfrag*)(pa0 + kc * 32);
            bfrag a1 = *(const bfrag*)(pa1 + kc * 32);
            bfrag b0 = *(const bfrag*)(pb0 + kc * 32);
            bfrag b1 = *(const bfrag*)(pb1 + kc * 32);
            acc00 = __builtin_amdgcn_mfma_f32_16x16x32_bf16(a0, b0, acc00, 0, 0, 0);
            acc01 = __builtin_amdgcn_mfma_f32_16x16x32_bf16(a0, b1, acc01, 0, 0, 0);
            acc10 = __builtin_amdgcn_mfma_f32_16x16x32_bf16(a1, b0, acc10, 0, 0, 0);
            acc11 = __builtin_amdgcn_mfma_f32_16x16x32_bf16(a1, b1, acc11, 0, 0, 0);
        }

        const float t0 = fast_tanh(g_val[eb + m]);
        const float t1 = fast_tanh(g_val[eb + 16 + m]);
        #pragma unroll
        for (int reg = 0; reg < 4; ++reg) {
            int r0 = sb + 4 * q + reg, r1 = r0 + 16;
            dv[(size_t)r0 * D_ + eb + m]      = acc00[reg] * t0;
            dv[(size_t)r0 * D_ + eb + 16 + m] = acc01[reg] * t1;
            dv[(size_t)r1 * D_ + eb + m]      = acc10[reg] * t0;
            dv[(size_t)r1 * D_ + eb + 16 + m] = acc11[reg] * t1;
        }
    }
}

extern "C" void kernel_launch(void* const* d_in, const int* in_sizes, int n_in,
                              void* d_out, int out_size, void* d_ws, size_t ws_size,
                              hipStream_t stream)
{
    (void)in_sizes; (void)n_in; (void)out_size; (void)ws_size;
    const float* hs   = (const float*)d_in[0];
    const float* qb   = (const float*)d_in[1];
    const float* kb   = (const float*)d_in[2];
    const float* gam  = (const float*)d_in[3];
    const float* bet  = (const float*)d_in[4];
    const float* W1   = (const float*)d_in[5];
    const float* W2   = (const float*)d_in[6];
    const float* Wq   = (const float*)d_in[7];
    const float* Wk   = (const float*)d_in[8];
    const float* Wv   = (const float*)d_in[9];
    const float* relb = (const float*)d_in[10];
    const float* ga   = (const float*)d_in[11];
    const float* gr   = (const float*)d_in[12];
    const float* gv   = (const float*)d_in[13];

    // ws layout
    unsigned short* Avb = (unsigned short*)d_ws;              // 512*768
    unsigned short* Wvb = Avb + (size_t)S_ * D_;              // 768*768
    unsigned short* Lb  = Wvb + (size_t)D_ * D_;              // 12*512*384
    unsigned short* Rb  = Lb + (size_t)NH * S_ * 384;         // 12*512*384
    float* Jv   = (float*)(Rb + (size_t)NH * S_ * 384);       // 12*512
    float* Iv   = Jv + NH * S_;                               // 12*512

    float* gauge = (float*)d_out;                             // 12*512*512
    float* dv   = gauge + (size_t)NH * S_ * S_;               // 512*768
    float* hbuf = dv;                                         // h in dv slot (dead before k_mm)

    k_ln   <<<dim3(128),        dim3(256), 0, stream>>>(hs, gam, bet, W1, Wv, Wvb, hbuf);
    k_amix <<<dim3(288),        dim3(256), 0, stream>>>(hbuf, W2, Wq, Wk, ga, qb, kb, relb, gr,
                                                        Avb, Lb, Rb, Jv, Iv);
    k_mm   <<<dim3(12, 8, 13),  dim3(256), 0, stream>>>(Lb, Rb, Jv, Iv, Avb, Wvb, gv, gauge, dv);
}

// Round 9
// 131.112 us; speedup vs baseline: 1.0131x; 1.0131x over previous
//
#include <hip/hip_runtime.h>

#define S_ 512
#define D_ 768
#define NH 12
#define HD 64
#define RK 16
#define D3 2304
#define LN_EPS 1e-5f

// odd Taylor tanh coefficients (deg-5; |d|<~0.35)
#define C3B (-0.3333333433f)
#define C5B (0.1333333403f)

typedef __attribute__((ext_vector_type(8))) short bfrag;
typedef __attribute__((ext_vector_type(4))) float ffrag;

__device__ __forceinline__ unsigned short f2bf(float f) {
    unsigned int u = __float_as_uint(f);
    unsigned int r = (u + 0x7FFFu + ((u >> 16) & 1u)) >> 16;   // RNE
    return (unsigned short)r;
}

// Pade [3/4] tanh for g_val (|x|<=0.02)
__device__ __forceinline__ float fast_tanh(float x) {
    float x2 = x * x;
    float num = x * __fmaf_rn(x2, 10.f, 105.f);
    float den = __fmaf_rn(x2 + 45.f, x2, 105.f);
    return num * __builtin_amdgcn_rcpf(den);
}

// ---------------- Kernel 1: LayerNorm + h = silu(xn @ W1^T), one wave/row;
// also packs Wv -> bf16 (independent side job) -------------------------------
__global__ __launch_bounds__(256) void k_ln(
    const float* __restrict__ x, const float* __restrict__ gamma,
    const float* __restrict__ beta, const float* __restrict__ W1,
    const float* __restrict__ Wv, unsigned short* __restrict__ Wvb,
    float* __restrict__ hout)
{
    const int row = blockIdx.x * 4 + (threadIdx.x >> 6);
    const int lane = threadIdx.x & 63;
    const float4* xr = (const float4*)(x + (size_t)row * D_);
    float4 a = xr[lane], b = xr[lane + 64], c = xr[lane + 128];
    float s = a.x + a.y + a.z + a.w + b.x + b.y + b.z + b.w + c.x + c.y + c.z + c.w;
    float sq = a.x*a.x + a.y*a.y + a.z*a.z + a.w*a.w
             + b.x*b.x + b.y*b.y + b.z*b.z + b.w*b.w
             + c.x*c.x + c.y*c.y + c.z*c.z + c.w*c.w;
    #pragma unroll
    for (int m = 1; m < 64; m <<= 1) { s += __shfl_xor(s, m); sq += __shfl_xor(sq, m); }
    float mean = s * (1.f / D_);
    float rstd = rsqrtf(sq * (1.f / D_) - mean * mean + LN_EPS);
    const float4* g4 = (const float4*)gamma;
    const float4* b4 = (const float4*)beta;
    float4 ga_ = g4[lane], gb_ = g4[lane + 64], gc_ = g4[lane + 128];
    float4 ba_ = b4[lane], bb_ = b4[lane + 64], bc_ = b4[lane + 128];
    float4 na, nb, nc;
    na.x = (a.x-mean)*rstd*ga_.x + ba_.x; na.y = (a.y-mean)*rstd*ga_.y + ba_.y;
    na.z = (a.z-mean)*rstd*ga_.z + ba_.z; na.w = (a.w-mean)*rstd*ga_.w + ba_.w;
    nb.x = (b.x-mean)*rstd*gb_.x + bb_.x; nb.y = (b.y-mean)*rstd*gb_.y + bb_.y;
    nb.z = (b.z-mean)*rstd*gb_.z + bb_.z; nb.w = (b.w-mean)*rstd*gb_.w + bb_.w;
    nc.x = (c.x-mean)*rstd*gc_.x + bc_.x; nc.y = (c.y-mean)*rstd*gc_.y + bc_.y;
    nc.z = (c.z-mean)*rstd*gc_.z + bc_.z; nc.w = (c.w-mean)*rstd*gc_.w + bc_.w;

    float hval = 0.f;
    #pragma unroll
    for (int r = 0; r < RK; ++r) {
        const float4* wr = (const float4*)(W1 + (size_t)r * D_);
        float4 wa = wr[lane], wb = wr[lane + 64], wc = wr[lane + 128];
        float p = na.x*wa.x + na.y*wa.y + na.z*wa.z + na.w*wa.w
                + nb.x*wb.x + nb.y*wb.y + nb.z*wb.z + nb.w*wb.w
                + nc.x*wc.x + nc.y*wc.y + nc.z*wc.z + nc.w*wc.w;
        #pragma unroll
        for (int m = 1; m < 64; m <<= 1) p += __shfl_xor(p, m);
        if (lane == r) hval = p;
    }
    if (lane < RK)
        hout[row * RK + lane] = hval * __builtin_amdgcn_rcpf(1.f + __expf(-hval));

    // Wv -> bf16 pack: 589824 elems / 32768 threads = 18 each
    const int gid = blockIdx.x * 256 + threadIdx.x;
    #pragma unroll
    for (int l = 0; l < 18; ++l)
        Wvb[gid + 32768 * l] = f2bf(Wv[gid + 32768 * l]);
}

// ---------------- Kernel 2: A-slice GEMM (K=16) fused with:
//  v-blocks : write bf16 Avb
//  q-blocks : L = [q | aqp'' | x | x^2 | x^3 | x^4], I[row] = -C5 sum w x^5
//  k-blocks : R = [akp'' | k | P1..P4],             J[row] = sum w(b+C3b^3+C5b^5)
//  aqp''/akp'' projection done with bf16 MFMA straight off At(LDS)+Wq/Wk(global)
__global__ __launch_bounds__(256) void k_amix(
    const float* __restrict__ h, const float* __restrict__ W2,
    const float* __restrict__ Wq, const float* __restrict__ Wk,
    const float* __restrict__ g_attn,
    const float* __restrict__ qb, const float* __restrict__ kb,
    const float* __restrict__ relb, const float* __restrict__ g_rel,
    unsigned short* __restrict__ Avb,
    unsigned short* __restrict__ L, unsigned short* __restrict__ R,
    float* __restrict__ J, float* __restrict__ I)
{
    __shared__ float hs[64 * 17];
    __shared__ float w2s[64 * 17];
    __shared__ float At[64 * 68];    // [s][dd]
    const int b = blockIdx.x;
    const int t = threadIdx.x;
    const int tx = t & 15, ty = t >> 4;

    int s0, c0, which = 0, hh = 0;
    bool qk = (b < 192);
    if (qk) { which = b & 1; hh = (b >> 1) % NH; s0 = ((b >> 1) / NH) * 64; c0 = which * D_ + hh * HD; }
    else    { int b2 = b - 192; s0 = (b2 / NH) * 64; hh = b2 % NH; c0 = 1536 + hh * HD; }

    {
        int r = t >> 2, q = (t & 3) * 4;
        float4 hv = *(const float4*)(h + (size_t)(s0 + r) * RK + q);
        hs[r*17+q] = hv.x; hs[r*17+q+1] = hv.y; hs[r*17+q+2] = hv.z; hs[r*17+q+3] = hv.w;
        float4 wv = *(const float4*)(W2 + (size_t)(c0 + r) * RK + q);
        w2s[r*17+q] = wv.x; w2s[r*17+q+1] = wv.y; w2s[r*17+q+2] = wv.z; w2s[r*17+q+3] = wv.w;
    }
    __syncthreads();

    float acc[4][4] = {};
    #pragma unroll
    for (int k = 0; k < RK; ++k) {
        float a0 = hs[(4*ty+0)*17+k], a1 = hs[(4*ty+1)*17+k];
        float a2 = hs[(4*ty+2)*17+k], a3 = hs[(4*ty+3)*17+k];
        float w0 = w2s[(4*tx+0)*17+k], w1 = w2s[(4*tx+1)*17+k];
        float w2v = w2s[(4*tx+2)*17+k], w3 = w2s[(4*tx+3)*17+k];
        acc[0][0]=__fmaf_rn(a0,w0,acc[0][0]); acc[0][1]=__fmaf_rn(a0,w1,acc[0][1]);
        acc[0][2]=__fmaf_rn(a0,w2v,acc[0][2]); acc[0][3]=__fmaf_rn(a0,w3,acc[0][3]);
        acc[1][0]=__fmaf_rn(a1,w0,acc[1][0]); acc[1][1]=__fmaf_rn(a1,w1,acc[1][1]);
        acc[1][2]=__fmaf_rn(a1,w2v,acc[1][2]); acc[1][3]=__fmaf_rn(a1,w3,acc[1][3]);
        acc[2][0]=__fmaf_rn(a2,w0,acc[2][0]); acc[2][1]=__fmaf_rn(a2,w1,acc[2][1]);
        acc[2][2]=__fmaf_rn(a2,w2v,acc[2][2]); acc[2][3]=__fmaf_rn(a2,w3,acc[2][3]);
        acc[3][0]=__fmaf_rn(a3,w0,acc[3][0]); acc[3][1]=__fmaf_rn(a3,w1,acc[3][1]);
        acc[3][2]=__fmaf_rn(a3,w2v,acc[3][2]); acc[3][3]=__fmaf_rn(a3,w3,acc[3][3]);
    }

    if (!qk) {   // value field -> bf16 Avb
        #pragma unroll
        for (int i = 0; i < 4; ++i) {
            ushort4 v = make_ushort4(f2bf(acc[i][0]), f2bf(acc[i][1]),
                                     f2bf(acc[i][2]), f2bf(acc[i][3]));
            *(ushort4*)(Avb + (size_t)(s0 + 4*ty + i) * D_ + hh * HD + 4*tx) = v;
        }
        return;
    }

    // stash A values for the MFMA projection phase
    #pragma unroll
    for (int i = 0; i < 4; ++i)
        *(float4*)(At + (4*ty + i) * 68 + 4*tx) =
            make_float4(acc[i][0], acc[i][1], acc[i][2], acc[i][3]);

    // raw base copy (q->L[0:64) or k->R[64:128)) — no LDS dependency
    {
        unsigned short* P = which ? R : L;
        const float* src = which ? kb : qb;
        const int segb = which ? 64 : 0;
        int r = t >> 2, cq = (t & 3) * 16;
        const float* sp = src + ((size_t)(hh * S_ + s0 + r)) * HD + cq;
        unsigned short* dp = P + ((size_t)(hh * S_ + s0 + r)) * 384 + segb + cq;
        #pragma unroll
        for (int u = 0; u < 4; ++u) {
            float4 v = *(const float4*)(sp + 4*u);
            *(ushort4*)(dp + 4*u) = make_ushort4(f2bf(v.x), f2bf(v.y), f2bf(v.z), f2bf(v.w));
        }
    }

    // per-dd weights w = relb * g_rel for this head
    float w_[4];
    {
        float grv = g_rel[hh];
        float4 rb4 = *(const float4*)(relb + hh * HD + 4*tx);
        w_[0] = rb4.x * grv; w_[1] = rb4.y * grv; w_[2] = rb4.z * grv; w_[3] = rb4.w * grv;
    }

    // power/poly segments + row-reduction partials
    float red[4];
    #pragma unroll
    for (int i = 0; i < 4; ++i) {
        size_t rb = ((size_t)(hh * S_ + s0 + 4*ty + i)) * 384;
        float partial = 0.f;
        ushort4 o1, o2, o3, o4;
        if (which == 0) {
            #pragma unroll
            for (int j = 0; j < 4; ++j) {
                float xv = acc[i][j];
                float x2 = xv*xv, x3 = x2*xv, x4 = x2*x2, x5 = x3*x2;
                ((unsigned short*)&o1)[j] = f2bf(xv);
                ((unsigned short*)&o2)[j] = f2bf(x2);
                ((unsigned short*)&o3)[j] = f2bf(x3);
                ((unsigned short*)&o4)[j] = f2bf(x4);
                partial += w_[j] * x5;
            }
            *(ushort4*)(L + rb + 128 + 4*tx) = o1;
            *(ushort4*)(L + rb + 192 + 4*tx) = o2;
            *(ushort4*)(L + rb + 256 + 4*tx) = o3;
            *(ushort4*)(L + rb + 320 + 4*tx) = o4;
        } else {
            #pragma unroll
            for (int j = 0; j < 4; ++j) {
                float bv = acc[i][j];
                float b2 = bv*bv, b3 = b2*bv, b4 = b2*b2, b5 = b3*b2;
                float w = w_[j];
                ((unsigned short*)&o1)[j] = f2bf(w * (-1.f - 3.f*C3B*b2 - 5.f*C5B*b4));
                ((unsigned short*)&o2)[j] = f2bf(w * (3.f*C3B*bv + 10.f*C5B*b3));
                ((unsigned short*)&o3)[j] = f2bf(w * (-C3B - 10.f*C5B*b2));
                ((unsigned short*)&o4)[j] = f2bf(w * (5.f*C5B*bv));
                partial += w * (bv + C3B*b3 + C5B*b5);
            }
            *(ushort4*)(R + rb + 128 + 4*tx) = o1;
            *(ushort4*)(R + rb + 192 + 4*tx) = o2;
            *(ushort4*)(R + rb + 256 + 4*tx) = o3;
            *(ushort4*)(R + rb + 320 + 4*tx) = o4;
        }
        red[i] = partial;
    }
    #pragma unroll
    for (int mm = 1; mm < 16; mm <<= 1) {
        #pragma unroll
        for (int i = 0; i < 4; ++i) red[i] += __shfl_xor(red[i], mm);
    }
    if (tx == 0) {
        #pragma unroll
        for (int i = 0; i < 4; ++i) {
            int row = hh * S_ + s0 + 4*ty + i;
            if (which == 0) I[row] = -C5B * red[i];
            else            J[row] = red[i];
        }
    }
    __syncthreads();   // At fully written before cross-wave MFMA reads

    // ---- MFMA projection: pacc[s][i] = sum_dd At[s][dd] * W[i][dd] ----
    {
        const float* Wsrc = which ? Wk : Wq;
        const int wave = t >> 6, lane = t & 63;
        const int wy = wave >> 1, wx = wave & 1;     // s-half, i-half
        const int m = lane & 15, q = lane >> 4;

        ffrag p00 = {0.f,0.f,0.f,0.f}, p01 = p00, p10 = p00, p11 = p00;
        #pragma unroll
        for (int kc = 0; kc < 2; ++kc) {
            const int dd0 = 32 * kc + 8 * q;
            const float* ar0 = At + (32*wy + m) * 68 + dd0;
            const float* ar1 = At + (32*wy + 16 + m) * 68 + dd0;
            const float* br0 = Wsrc + (size_t)(32*wx + m) * HD + dd0;
            const float* br1 = Wsrc + (size_t)(32*wx + 16 + m) * HD + dd0;
            bfrag a0, a1, b0, b1;
            #pragma unroll
            for (int e = 0; e < 8; ++e) {
                a0[e] = (short)f2bf(ar0[e]);
                a1[e] = (short)f2bf(ar1[e]);
                b0[e] = (short)f2bf(br0[e]);
                b1[e] = (short)f2bf(br1[e]);
            }
            p00 = __builtin_amdgcn_mfma_f32_16x16x32_bf16(a0, b0, p00, 0, 0, 0);
            p01 = __builtin_amdgcn_mfma_f32_16x16x32_bf16(a0, b1, p01, 0, 0, 0);
            p10 = __builtin_amdgcn_mfma_f32_16x16x32_bf16(a1, b0, p10, 0, 0, 0);
            p11 = __builtin_amdgcn_mfma_f32_16x16x32_bf16(a1, b1, p11, 0, 0, 0);
        }

        const float sc = 0.125f * g_attn[hh];
        const int i0c = 32*wx + m, i1c = i0c + 16;
        unsigned short* P = which ? R : L;
        const int segb = which ? 0 : 64;
        #pragma unroll
        for (int reg = 0; reg < 4; ++reg) {
            int sr0 = 32*wy + 4*q + reg, sr1 = sr0 + 16;
            size_t r0 = ((size_t)(hh * S_ + s0 + sr0)) * 384 + segb;
            size_t r1 = ((size_t)(hh * S_ + s0 + sr1)) * 384 + segb;
            P[r0 + i0c] = f2bf(p00[reg] * sc);
            P[r0 + i1c] = f2bf(p01[reg] * sc);
            P[r1 + i0c] = f2bf(p10[reg] * sc);
            P[r1 + i1c] = f2bf(p11[reg] * sc);
        }
    }
}

// ---------------- Kernel 3: merged MFMA kernel, compact grid (108 x 8).
//  bx < 96 : gauge[h=bx>>3] tile (it=by, jt=bx&7) = L @ R^T (K=384) + J + I
//  bx >= 96: dv tile (et=bx-96, st=by) = tanh(g_val) * (Avb @ Wvb^T) (K=768)
__global__ __launch_bounds__(256) void k_mm(
    const unsigned short* __restrict__ L, const unsigned short* __restrict__ R,
    const float* __restrict__ J, const float* __restrict__ I,
    const unsigned short* __restrict__ Avb, const unsigned short* __restrict__ Wvb,
    const float* __restrict__ g_val,
    float* __restrict__ out, float* __restrict__ dv)
{
    const int bx = blockIdx.x;
    const int t = threadIdx.x;
    const int wave = t >> 6, lane = t & 63;
    const int wy = wave >> 1, wx = wave & 1;
    const int m = lane & 15, q = lane >> 4;

    ffrag acc00 = {0.f,0.f,0.f,0.f}, acc01 = acc00, acc10 = acc00, acc11 = acc00;

    if (bx < 96) {
        const int h = bx >> 3;
        const int ib = blockIdx.y * 64 + wy * 32, jb = (bx & 7) * 64 + wx * 32;

        const unsigned short* pa0 = L + ((size_t)(h * S_) + ib + m) * 384 + 8 * q;
        const unsigned short* pa1 = pa0 + 16 * 384;
        const unsigned short* pb0 = R + ((size_t)(h * S_) + jb + m) * 384 + 8 * q;
        const unsigned short* pb1 = pb0 + 16 * 384;

        #pragma unroll
        for (int kc = 0; kc < 12; ++kc) {
            bfrag a0 = *(const bfrag*)(pa0 + kc * 32);
            bfrag a1 = *(const bfrag*)(pa1 + kc * 32);
            bfrag b0 = *(const bfrag*)(pb0 + kc * 32);
            bfrag b1 = *(const bfrag*)(pb1 + kc * 32);
            acc00 = __builtin_amdgcn_mfma_f32_16x16x32_bf16(a0, b0, acc00, 0, 0, 0);
            acc01 = __builtin_amdgcn_mfma_f32_16x16x32_bf16(a0, b1, acc01, 0, 0, 0);
            acc10 = __builtin_amdgcn_mfma_f32_16x16x32_bf16(a1, b0, acc10, 0, 0, 0);
            acc11 = __builtin_amdgcn_mfma_f32_16x16x32_bf16(a1, b1, acc11, 0, 0, 0);
        }

        const float Jc0 = J[h * S_ + jb + m];
        const float Jc1 = J[h * S_ + jb + 16 + m];
        float* ob = out + ((size_t)h * S_) * S_;
        #pragma unroll
        for (int reg = 0; reg < 4; ++reg) {
            int r0 = ib + 4 * q + reg, r1 = r0 + 16;
            float i0v = I[h * S_ + r0];
            ob[(size_t)r0 * S_ + jb + m]      = acc00[reg] + Jc0 + i0v;
            ob[(size_t)r0 * S_ + jb + 16 + m] = acc01[reg] + Jc1 + i0v;
            float i1v = I[h * S_ + r1];
            ob[(size_t)r1 * S_ + jb + m]      = acc10[reg] + Jc0 + i1v;
            ob[(size_t)r1 * S_ + jb + 16 + m] = acc11[reg] + Jc1 + i1v;
        }
    } else {
        // delta_v tile: rows = s, cols = e, K = 768
        const int sb = blockIdx.y * 64 + wy * 32, eb = (bx - 96) * 64 + wx * 32;

        const unsigned short* pa0 = Avb + (size_t)(sb + m) * D_ + 8 * q;
        const unsigned short* pa1 = pa0 + 16 * D_;
        const unsigned short* pb0 = Wvb + (size_t)(eb + m) * D_ + 8 * q;
        const unsigned short* pb1 = pb0 + 16 * D_;

        #pragma unroll 6
        for (int kc = 0; kc < 24; ++kc) {
            bfrag a0 = *(const bfrag*)(pa0 + kc * 32);
            bfrag a1 = *(const bfrag*)(pa1 + kc * 32);
            bfrag b0 = *(const bfrag*)(pb0 + kc * 32);
            bfrag b1 = *(const bfrag*)(pb1 + kc * 32);
            acc00 = __builtin_amdgcn_mfma_f32_16x16x32_bf16(a0, b0, acc00, 0, 0, 0);
            acc01 = __builtin_amdgcn_mfma_f32_16x16x32_bf16(a0, b1, acc01, 0, 0, 0);
            acc10 = __builtin_amdgcn_mfma_f32_16x16x32_bf16(a1, b0, acc10, 0, 0, 0);
            acc11 = __builtin_amdgcn_mfma_f32_16x16x32_bf16(a1, b1, acc11, 0, 0, 0);
        }

        const float t0 = fast_tanh(g_val[eb + m]);
        const float t1 = fast_tanh(g_val[eb + 16 + m]);
        #pragma unroll
        for (int reg = 0; reg < 4; ++reg) {
            int r0 = sb + 4 * q + reg, r1 = r0 + 16;
            dv[(size_t)r0 * D_ + eb + m]      = acc00[reg] * t0;
            dv[(size_t)r0 * D_ + eb + 16 + m] = acc01[reg] * t1;
            dv[(size_t)r1 * D_ + eb + m]      = acc10[reg] * t0;
            dv[(size_t)r1 * D_ + eb + 16 + m] = acc11[reg] * t1;
        }
    }
}

extern "C" void kernel_launch(void* const* d_in, const int* in_sizes, int n_in,
                              void* d_out, int out_size, void* d_ws, size_t ws_size,
                              hipStream_t stream)
{
    (void)in_sizes; (void)n_in; (void)out_size; (void)ws_size;
    const float* hs   = (const float*)d_in[0];
    const float* qb   = (const float*)d_in[1];
    const float* kb   = (const float*)d_in[2];
    const float* gam  = (const float*)d_in[3];
    const float* bet  = (const float*)d_in[4];
    const float* W1   = (const float*)d_in[5];
    const float* W2   = (const float*)d_in[6];
    const float* Wq   = (const float*)d_in[7];
    const float* Wk   = (const float*)d_in[8];
    const float* Wv   = (const float*)d_in[9];
    const float* relb = (const float*)d_in[10];
    const float* ga   = (const float*)d_in[11];
    const float* gr   = (const float*)d_in[12];
    const float* gv   = (const float*)d_in[13];

    // ws layout
    unsigned short* Avb = (unsigned short*)d_ws;              // 512*768
    unsigned short* Wvb = Avb + (size_t)S_ * D_;              // 768*768
    unsigned short* Lb  = Wvb + (size_t)D_ * D_;              // 12*512*384
    unsigned short* Rb  = Lb + (size_t)NH * S_ * 384;         // 12*512*384
    float* Jv   = (float*)(Rb + (size_t)NH * S_ * 384);       // 12*512
    float* Iv   = Jv + NH * S_;                               // 12*512

    float* gauge = (float*)d_out;                             // 12*512*512
    float* dv   = gauge + (size_t)NH * S_ * S_;               // 512*768
    float* hbuf = dv;                                         // h in dv slot (dead before k_mm)

    k_ln   <<<dim3(128),      dim3(256), 0, stream>>>(hs, gam, bet, W1, Wv, Wvb, hbuf);
    k_amix <<<dim3(288),      dim3(256), 0, stream>>>(hbuf, W2, Wq, Wk, ga, qb, kb, relb, gr,
                                                      Avb, Lb, Rb, Jv, Iv);
    k_mm   <<<dim3(108, 8),   dim3(256), 0, stream>>>(Lb, Rb, Jv, Iv, Avb, Wvb, gv, gauge, dv);
}